// Round 11
// baseline (685.244 us; speedup 1.0000x reference)
//
#include <hip/hip_runtime.h>
#include <math.h>

#define BATCH 8
#define H 256
#define W 256
#define HW (H*W)
#define KS 9
#define NSTEP 50   // 50 launches x 2 fused iterations = 100

struct GaussW { float g[KS]; };

__device__ __forceinline__ int refl(int i, int n) {
    if (i < 0) i = -i;
    if (i >= n) i = 2*n - 2 - i;
    return i;
}

__device__ __forceinline__ float4 ld4s(const float* p) { return *(const float4*)p; }
__device__ __forceinline__ void st4s(float* p, float4 v) { *(float4*)p = v; }
__device__ __forceinline__ float4 f4mul(float a, float4 x) {
    return make_float4(a*x.x, a*x.y, a*x.z, a*x.w);
}
__device__ __forceinline__ float4 f4fma(float a, float4 x, float4 y) {
    return make_float4(fmaf(a,x.x,y.x), fmaf(a,x.y,y.y), fmaf(a,x.z,y.z), fmaf(a,x.w,y.w));
}

#if defined(__has_builtin)
#  if __has_builtin(__builtin_amdgcn_exp2f)
#    define FEXP2(x) __builtin_amdgcn_exp2f(x)
#  endif
#  if __has_builtin(__builtin_amdgcn_sqrtf)
#    define FSQRT(x) __builtin_amdgcn_sqrtf(x)
#  endif
#endif
#ifndef FEXP2
#  define FEXP2(x) exp2f(x)
#endif
#ifndef FSQRT
#  define FSQRT(x) sqrtf(x)
#endif

// eig + diffusion update. kc = log2(e)/k^2 so exp(-lam^2/k^2) = exp2(-lam^2*kc)
__device__ __forceinline__ float diffuse(float s11, float s12, float s22,
                                         float rv, float u0, float dt, float kc) {
    s11 -= rv; s12 -= rv; s22 -= rv;
    float df = s11 - s22;
    float tm = FSQRT(fmaf(df, df, 4.f*s12*s12));
    float sm = s11 + s22;
    float lam1 = 0.5f*(sm + tm);
    float lam2 = 0.5f*(sm - tm);
    float e1 = FEXP2(-(lam1*lam1)*kc);
    float e2 = FEXP2(-(lam2*lam2)*kc);
    return fmaf(dt, fmaf(e1, lam1, e2*lam2), u0);
}

// register-sliding vertical 9-tap blur strip (b128 LDS in/out)
template<int N>
__device__ __forceinline__ void vblur_strip(const float* __restrict__ P, float* __restrict__ V,
                                            int qoff, int r0, const GaussW gw, int stride) {
    const float* s = P + r0*stride + qoff;
    float4 w0 = ld4s(s); s += stride;
    float4 w1 = ld4s(s); s += stride;
    float4 w2 = ld4s(s); s += stride;
    float4 w3 = ld4s(s); s += stride;
    float4 w4 = ld4s(s); s += stride;
    float4 w5 = ld4s(s); s += stride;
    float4 w6 = ld4s(s); s += stride;
    float4 w7 = ld4s(s); s += stride;
    float* d = V + r0*stride + qoff;
#pragma unroll
    for (int j = 0; j < N; ++j) {
        float4 w8 = ld4s(s); s += stride;
        float4 o = f4mul(gw.g[0], w0);
        o = f4fma(gw.g[1], w1, o);
        o = f4fma(gw.g[2], w2, o);
        o = f4fma(gw.g[3], w3, o);
        o = f4fma(gw.g[4], w4, o);
        o = f4fma(gw.g[5], w5, o);
        o = f4fma(gw.g[6], w6, o);
        o = f4fma(gw.g[7], w7, o);
        o = f4fma(gw.g[8], w8, o);
        st4s(d, o); d += stride;
        w0=w1; w1=w2; w2=w3; w3=w4; w4=w5; w5=w6; w6=w7; w7=w8;
    }
}

// ---------------- fused pre-kernel: luma + gauss_rho (proven r5-r9) ----------------
__global__ void __launch_bounds__(512) pre_kernel(const float* __restrict__ x,
                                                  float* __restrict__ u0,
                                                  float* __restrict__ rho, GaussW gw) {
    __shared__ __align__(16) float lum[24*76];
    __shared__ __align__(16) float vb[16*72];
    const int tid = threadIdx.x;
    const int X0 = blockIdx.x*64, Y0 = blockIdx.y*16, b = blockIdx.z;
    const float* xb = x + (size_t)b*3*HW;

    if (tid < 24*18) {
        int r = tid/18, qc = tid - r*18;
        int gy = refl(Y0-4+r, H);
        int gc0 = X0-4+4*qc;
        float4 R,G,B;
        if (gc0 >= 0 && gc0+3 <= W-1) {
            const float* px = xb + gy*W + gc0;
            R = ld4s(px); G = ld4s(px+HW); B = ld4s(px+2*HW);
        } else {
            float rr[4], gg[4], bb[4];
#pragma unroll
            for (int j=0;j<4;++j){ int gc = refl(gc0+j, W);
                rr[j]=xb[gy*W+gc]; gg[j]=xb[HW+gy*W+gc]; bb[j]=xb[2*HW+gy*W+gc]; }
            R = make_float4(rr[0],rr[1],rr[2],rr[3]);
            G = make_float4(gg[0],gg[1],gg[2],gg[3]);
            B = make_float4(bb[0],bb[1],bb[2],bb[3]);
        }
        float4 L = make_float4(0.299f*R.x+0.587f*G.x+0.114f*B.x,
                               0.299f*R.y+0.587f*G.y+0.114f*B.y,
                               0.299f*R.z+0.587f*G.z+0.114f*B.z,
                               0.299f*R.w+0.587f*G.w+0.114f*B.w);
        st4s(lum + r*76 + 4*qc, L);
    }
    __syncthreads();
    if (tid < 16*18) {
        int r = tid/18, qc = tid - r*18;
        const float* s = lum + r*76 + 4*qc;
        float4 o = f4mul(gw.g[0], ld4s(s));
#pragma unroll
        for (int t = 1; t < KS; ++t) o = f4fma(gw.g[t], ld4s(s + t*76), o);
        st4s(vb + r*72 + 4*qc, o);
    }
    __syncthreads();
    if (tid < 256) {
        int r = tid>>4, c4 = tid&15;
        const float* s = vb + r*72 + 4*c4;
        float4 q0=ld4s(s), q1=ld4s(s+4), q2=ld4s(s+8);
        float f[12]={q0.x,q0.y,q0.z,q0.w,q1.x,q1.y,q1.z,q1.w,q2.x,q2.y,q2.z,q2.w};
        float o[4];
#pragma unroll
        for (int j=0;j<4;++j) {
            float a = gw.g[0]*f[j];
#pragma unroll
            for (int t=1;t<KS;++t) a = fmaf(gw.g[t], f[j+t], a);
            o[j] = a;
        }
        int gidx = b*HW + (Y0+r)*W + X0 + 4*c4;
        st4s(rho + gidx, make_float4(o[0],o[1],o[2],o[3]));
        st4s(u0 + gidx, ld4s(lum + (r+4)*76 + 4*c4 + 4));
    }
}

// ---------------- fused 2-iteration step, tile 64x32, 1024 threads, 6 phases ----
// r9 structure; products stored at reflect-mapped columns in A/A2 (scalar path for
// straddling groups on edge blocks) so V/V2 are fully uniform -- no ghost-col
// mirror items, no strip skips, identical work on every block.
// Dynamic LDS (floats), total 24288 (97152 B):
//   p  @0     : 3 x 50x88 (stride 4400)   rows [Y0-9..Y0+41) cols [X0-12..X0+76)
//   v  @13200 : 3 x 42x88 (stride 3696)   rows [Y0-5..Y0+37)
//   u1 @0     : 42x80 (overlays p, dead)  cols [X0-8..X0+72)
//   q  @3360  : 3 x 40x72 (stride 2880)   rows [Y0-4..Y0+36) cols [X0-4..X0+68)
//   w  @13200 : 3 x 32x72 (stride 2304)   rows [Y0..Y0+32)   (overlays v, dead)
#define STEP_LDS_FL 24288
template<bool LAST>
__global__ void __launch_bounds__(1024, 4) step2_kernel(
        const float* __restrict__ uin, float* __restrict__ uout,
        const float* __restrict__ rho,
        const float* __restrict__ dtp, const float* __restrict__ kp,
        GaussW gw)
{
    extern __shared__ __align__(16) float lds[];
    float* p_ = lds;             // 3 x 50x88
    float* v_ = lds + 13200;     // 3 x 42x88
    float* u1 = lds;             // 42x80
    float* q_ = lds + 3360;      // 3 x 40x72
    float* w_ = lds + 13200;     // 3 x 32x72

    const int tid = threadIdx.x;
    const int X0 = blockIdx.x*64, Y0 = blockIdx.y*32, b = blockIdx.z;
    const float* ub = uin + b*HW;
    const float* rb = rho + b*HW;
    const float dt = *dtp;
    const float kk = *kp;
    const float kc = 1.4426950408889634f / (kk*kk);
    const bool eL = (X0 == 0), eR = (X0 == W-64);
    const float4 f4z = make_float4(0.f,0.f,0.f,0.f);

    // ---- Phase A: iter1 Sobel products at reflect-mapped row+col coords -> p
    if (tid < 550) {
        int pr = tid / 11, cg = tid - pr*11;
        int p0 = refl(Y0 - 9 + pr, H);
        const float* rc = ub + p0*W;
        const float* rm = rc - W;
        const float* rp = rc + W;
        bool mok = (p0 > 0), pok = (p0 < H-1);
        float o11[8], o12[8], o22[8];
        bool scalar = (eL && cg < 2) || (eR && cg > 8);
        if (!scalar) {
            int c0 = X0 - 12 + 8*cg;   // all source cols [c0-4, c0+11] provably in [0,W)
            float4 Am = mok?ld4s(rm+c0-4):f4z, Bm = mok?ld4s(rm+c0):f4z;
            float4 Cm = mok?ld4s(rm+c0+4):f4z, Dm = mok?ld4s(rm+c0+8):f4z;
            float4 Ac = ld4s(rc+c0-4), Bc = ld4s(rc+c0), Cc = ld4s(rc+c0+4), Dc = ld4s(rc+c0+8);
            float4 Ap = pok?ld4s(rp+c0-4):f4z, Bp = pok?ld4s(rp+c0):f4z;
            float4 Cp = pok?ld4s(rp+c0+4):f4z, Dp = pok?ld4s(rp+c0+8):f4z;
            float fm[10]={Am.w,Bm.x,Bm.y,Bm.z,Bm.w,Cm.x,Cm.y,Cm.z,Cm.w,Dm.x};
            float fc[10]={Ac.w,Bc.x,Bc.y,Bc.z,Bc.w,Cc.x,Cc.y,Cc.z,Cc.w,Dc.x};
            float fp[10]={Ap.w,Bp.x,Bp.y,Bp.z,Bp.w,Cp.x,Cp.y,Cp.z,Cp.w,Dp.x};
#pragma unroll
            for (int j=0;j<8;++j) {
                float gx = (fm[j+2]-fm[j]) + 2.f*(fc[j+2]-fc[j]) + (fp[j+2]-fp[j]);
                float gy = (fp[j]-fm[j]) + 2.f*(fp[j+1]-fm[j+1]) + (fp[j+2]-fm[j+2]);
                o11[j]=gx*gx; o12[j]=gx*gy; o22[j]=gy*gy;
            }
        } else {
            // edge-block straddling groups: product at reflected col, scalar per elem
#pragma unroll
            for (int j=0;j<8;++j) {
                int xc = X0 - 12 + 8*cg + j;
                int xm = refl(xc, W);
                bool lok = (xm > 0), rok = (xm < W-1);
                float uml = (mok&&lok)?rm[xm-1]:0.f, umc = mok?rm[xm]:0.f, umr = (mok&&rok)?rm[xm+1]:0.f;
                float ucl = lok?rc[xm-1]:0.f,                               ucr = rok?rc[xm+1]:0.f;
                float upl = (pok&&lok)?rp[xm-1]:0.f, upc = pok?rp[xm]:0.f, upr = (pok&&rok)?rp[xm+1]:0.f;
                float gx = (umr-uml) + 2.f*(ucr-ucl) + (upr-upl);
                float gy = (upl-uml) + 2.f*(upc-umc) + (upr-umr);
                o11[j]=gx*gx; o12[j]=gx*gy; o22[j]=gy*gy;
            }
        }
        int o = pr*88 + 8*cg;
        st4s(p_+o,        make_float4(o11[0],o11[1],o11[2],o11[3]));
        st4s(p_+o+4,      make_float4(o11[4],o11[5],o11[6],o11[7]));
        st4s(p_+4400+o,   make_float4(o12[0],o12[1],o12[2],o12[3]));
        st4s(p_+4400+o+4, make_float4(o12[4],o12[5],o12[6],o12[7]));
        st4s(p_+8800+o,   make_float4(o22[0],o22[1],o22[2],o22[3]));
        st4s(p_+8800+o+4, make_float4(o22[4],o22[5],o22[6],o22[7]));
    }
    __syncthreads();

    // ---- Phase V: iter1 vertical blur -- fully uniform (3-row strips, 924 items)
    if (tid < 924) {
        int cg = tid % 22; int t = tid / 22; int strip = t % 14; int pl = t / 14;
        vblur_strip<3>(p_ + pl*4400, v_ + pl*3696, 4*cg, strip*3, gw, 88);
    }
    __syncthreads();

    // ---- Phase H: iter1 horizontal blur + eig + update -> u1 (4px/item, 840 items)
    if (tid < 840) {
        int r = tid/20, qc = tid - r*20;      // r 0..41, qc 0..19
        int uy = Y0-5+r;
        int c0 = X0-8+4*qc;
        float acc[3][4];
#pragma unroll
        for (int pl=0; pl<3; ++pl) {
            const float* Vp = v_ + pl*3696 + r*88 + 4*qc;
            float4 q0=ld4s(Vp), q1=ld4s(Vp+4), q2=ld4s(Vp+8);
            float f[12]={q0.x,q0.y,q0.z,q0.w,q1.x,q1.y,q1.z,q1.w,q2.x,q2.y,q2.z,q2.w};
#pragma unroll
            for (int j=0;j<4;++j) {
                float s = gw.g[0]*f[j];
#pragma unroll
                for (int t=1;t<KS;++t) s = fmaf(gw.g[t], f[j+t], s);
                acc[pl][j] = s;
            }
        }
        bool in0 = (uy>=0 && uy<H) && c0>=0 && c0<=W-4;
        float4 rv0=f4z, uq0=f4z;
        if (in0) { rv0 = ld4s(rb+uy*W+c0); uq0 = ld4s(ub+uy*W+c0); }
        float rva[4]={rv0.x,rv0.y,rv0.z,rv0.w};
        float uqa[4]={uq0.x,uq0.y,uq0.z,uq0.w};
        float res[4];
#pragma unroll
        for (int j=0;j<4;++j)
            res[j] = diffuse(acc[0][j],acc[1][j],acc[2][j],rva[j],uqa[j],dt,kc);
        st4s(u1 + r*80 + 4*qc,
             in0 ? make_float4(res[0],res[1],res[2],res[3]) : f4z);
    }
    __syncthreads();

    // ---- Phase A2: iter2 Sobel products from u1 at reflect-mapped cols (720 items)
    if (tid < 720) {
        int pr = tid/18, cg = tid - pr*18;    // pr 0..39, cg 0..17
        int sr = refl(Y0-4+pr, H) - (Y0-5);   // in [1,40]
        const float* rmw = u1 + (sr-1)*80;
        const float* rcw = rmw + 80;
        const float* rpw = rcw + 80;
        float o11[4],o12[4],o22[4];
        bool scalar = (eL && cg==0) || (eR && cg==17);
        if (!scalar) {
            const float* m4 = rmw + 4*cg;
            const float* c4p = rcw + 4*cg;
            const float* p4 = rpw + 4*cg;
            float4 Am=ld4s(m4), Bm=ld4s(m4+4), Cm=ld4s(m4+8);
            float4 Ac=ld4s(c4p), Bc=ld4s(c4p+4), Cc=ld4s(c4p+8);
            float4 Ap=ld4s(p4), Bp=ld4s(p4+4), Cp=ld4s(p4+8);
            float fm[6]={Am.w,Bm.x,Bm.y,Bm.z,Bm.w,Cm.x};
            float fc[6]={Ac.w,Bc.x,Bc.y,Bc.z,Bc.w,Cc.x};
            float fp[6]={Ap.w,Bp.x,Bp.y,Bp.z,Bp.w,Cp.x};
#pragma unroll
            for (int j=0;j<4;++j) {
                float gx = (fm[j+2]-fm[j]) + 2.f*(fc[j+2]-fc[j]) + (fp[j+2]-fp[j]);
                float gy = (fp[j]-fm[j]) + 2.f*(fp[j+1]-fm[j+1]) + (fp[j+2]-fm[j+2]);
                o11[j]=gx*gx; o12[j]=gx*gy; o22[j]=gy*gy;
            }
        } else {
#pragma unroll
            for (int j=0;j<4;++j) {
                int xc = X0 - 4 + 4*cg + j;
                int uc = refl(xc, W) - X0 + 8;    // u1-space col (ghost zeros give pad)
                float gx = (rmw[uc+1]-rmw[uc-1]) + 2.f*(rcw[uc+1]-rcw[uc-1]) + (rpw[uc+1]-rpw[uc-1]);
                float gy = (rpw[uc-1]-rmw[uc-1]) + 2.f*(rpw[uc]-rmw[uc]) + (rpw[uc+1]-rmw[uc+1]);
                o11[j]=gx*gx; o12[j]=gx*gy; o22[j]=gy*gy;
            }
        }
        int o = pr*72 + 4*cg;
        st4s(q_+o,      make_float4(o11[0],o11[1],o11[2],o11[3]));
        st4s(q_+2880+o, make_float4(o12[0],o12[1],o12[2],o12[3]));
        st4s(q_+5760+o, make_float4(o22[0],o22[1],o22[2],o22[3]));
    }
    __syncthreads();

    // ---- Phase V2: iter2 vertical blur -- fully uniform (4-row strips, 432 items)
    if (tid < 432) {
        int cg = tid % 18; int t = tid/18; int strip = t % 8; int pl = t/8;
        vblur_strip<4>(q_ + pl*2880, w_ + pl*2304, 4*cg, strip*4, gw, 72);
    }
    __syncthreads();

    // ---- Phase H2: iter2 horizontal blur + eig + update -> global (512 items)
    if (tid < 512) {
        int r = tid>>4, c4 = tid&15;
        float acc[3][4];
#pragma unroll
        for (int pl=0; pl<3; ++pl) {
            const float* Vp = w_ + pl*2304 + r*72 + 4*c4;
            float4 q0=ld4s(Vp), q1=ld4s(Vp+4), q2=ld4s(Vp+8);
            float f[12]={q0.x,q0.y,q0.z,q0.w,q1.x,q1.y,q1.z,q1.w,q2.x,q2.y,q2.z,q2.w};
#pragma unroll
            for (int j=0;j<4;++j) {
                float s = gw.g[0]*f[j];
#pragma unroll
                for (int t=1;t<KS;++t) s = fmaf(gw.g[t], f[j+t], s);
                acc[pl][j] = s;
            }
        }
        int gidx = (Y0+r)*W + X0 + 4*c4;
        float4 rv = ld4s(rb + gidx);
        float4 uq = ld4s(u1 + (r+5)*80 + 4*c4 + 8);
        float rva[4]={rv.x,rv.y,rv.z,rv.w};
        float uqa[4]={uq.x,uq.y,uq.z,uq.w};
        float o[4];
#pragma unroll
        for (int j=0;j<4;++j)
            o[j] = diffuse(acc[0][j],acc[1][j],acc[2][j],rva[j],uqa[j],dt,kc);
        float4 ov = make_float4(o[0],o[1],o[2],o[3]);
        if (LAST) {
            float* ob = uout + (size_t)b*3*HW + gidx;
            st4s(ob, ov); st4s(ob+HW, ov); st4s(ob+2*HW, ov);
        } else {
            st4s(uout + b*HW + gidx, ov);
        }
    }
}

extern "C" void kernel_launch(void* const* d_in, const int* in_sizes, int n_in,
                              void* d_out, int out_size, void* d_ws, size_t ws_size,
                              hipStream_t stream) {
    const float* x   = (const float*)d_in[0];
    const float* dtp = (const float*)d_in[1];
    const float* kp  = (const float*)d_in[2];
    float* out = (float*)d_out;

    float* u_a = (float*)d_ws;
    float* u_b = u_a + BATCH*HW;
    float* rho = u_b + BATCH*HW;

    GaussW gw;
    {
        double s = 0.0, wd[KS];
        for (int i = 0; i < KS; ++i) {
            double xd = (double)i - 4.0;
            wd[i] = exp(-0.5 * (xd/4.0) * (xd/4.0));
            s += wd[i];
        }
        for (int i = 0; i < KS; ++i) gw.g[i] = (float)(wd[i] / s);
    }

    const int dyn_lds = STEP_LDS_FL * 4;   // 97152 B
    (void)hipFuncSetAttribute((const void*)step2_kernel<false>,
                              hipFuncAttributeMaxDynamicSharedMemorySize, dyn_lds);
    (void)hipFuncSetAttribute((const void*)step2_kernel<true>,
                              hipFuncAttributeMaxDynamicSharedMemorySize, dyn_lds);

    dim3 gpre(W/64, H/16, BATCH), bpre(512);
    pre_kernel<<<gpre, bpre, 0, stream>>>(x, u_a, rho, gw);

    dim3 gs(W/64, H/32, BATCH), bs(1024);
    float* cur = u_a;
    float* nxt = u_b;
    for (int it = 0; it < NSTEP-1; ++it) {
        step2_kernel<false><<<gs, bs, dyn_lds, stream>>>(cur, nxt, rho, dtp, kp, gw);
        float* t = cur; cur = nxt; nxt = t;
    }
    step2_kernel<true><<<gs, bs, dyn_lds, stream>>>(cur, out, rho, dtp, kp, gw);
}

// Round 12
// 573.180 us; speedup vs baseline: 1.1955x; 1.1955x over previous
//
#include <hip/hip_runtime.h>
#include <math.h>

#define BATCH 8
#define H 256
#define W 256
#define HW (H*W)
#define KS 9
#define NSTEP 50   // 50 launches x 2 fused iterations = 100

struct GaussW { float g[KS]; };

__device__ __forceinline__ int refl(int i, int n) {
    if (i < 0) i = -i;
    if (i >= n) i = 2*n - 2 - i;
    return i;
}

__device__ __forceinline__ float4 ld4s(const float* p) { return *(const float4*)p; }
__device__ __forceinline__ void st4s(float* p, float4 v) { *(float4*)p = v; }
__device__ __forceinline__ float4 f4mul(float a, float4 x) {
    return make_float4(a*x.x, a*x.y, a*x.z, a*x.w);
}
__device__ __forceinline__ float4 f4fma(float a, float4 x, float4 y) {
    return make_float4(fmaf(a,x.x,y.x), fmaf(a,x.y,y.y), fmaf(a,x.z,y.z), fmaf(a,x.w,y.w));
}

#if defined(__has_builtin)
#  if __has_builtin(__builtin_amdgcn_exp2f)
#    define FEXP2(x) __builtin_amdgcn_exp2f(x)
#  endif
#  if __has_builtin(__builtin_amdgcn_sqrtf)
#    define FSQRT(x) __builtin_amdgcn_sqrtf(x)
#  endif
#endif
#ifndef FEXP2
#  define FEXP2(x) exp2f(x)
#endif
#ifndef FSQRT
#  define FSQRT(x) sqrtf(x)
#endif

// eig + diffusion update. kc = log2(e)/k^2 so exp(-lam^2/k^2) = exp2(-lam^2*kc)
__device__ __forceinline__ float diffuse(float s11, float s12, float s22,
                                         float rv, float u0, float dt, float kc) {
    s11 -= rv; s12 -= rv; s22 -= rv;
    float df = s11 - s22;
    float tm = FSQRT(fmaf(df, df, 4.f*s12*s12));
    float sm = s11 + s22;
    float lam1 = 0.5f*(sm + tm);
    float lam2 = 0.5f*(sm - tm);
    float e1 = FEXP2(-(lam1*lam1)*kc);
    float e2 = FEXP2(-(lam2*lam2)*kc);
    return fmaf(dt, fmaf(e1, lam1, e2*lam2), u0);
}

// register-sliding vertical 9-tap blur strip (b128 LDS in/out)
template<int N>
__device__ __forceinline__ void vblur_strip(const float* __restrict__ P, float* __restrict__ V,
                                            int qoff, int r0, const GaussW gw, int stride) {
    const float* s = P + r0*stride + qoff;
    float4 w0 = ld4s(s); s += stride;
    float4 w1 = ld4s(s); s += stride;
    float4 w2 = ld4s(s); s += stride;
    float4 w3 = ld4s(s); s += stride;
    float4 w4 = ld4s(s); s += stride;
    float4 w5 = ld4s(s); s += stride;
    float4 w6 = ld4s(s); s += stride;
    float4 w7 = ld4s(s); s += stride;
    float* d = V + r0*stride + qoff;
#pragma unroll
    for (int j = 0; j < N; ++j) {
        float4 w8 = ld4s(s); s += stride;
        float4 o = f4mul(gw.g[0], w0);
        o = f4fma(gw.g[1], w1, o);
        o = f4fma(gw.g[2], w2, o);
        o = f4fma(gw.g[3], w3, o);
        o = f4fma(gw.g[4], w4, o);
        o = f4fma(gw.g[5], w5, o);
        o = f4fma(gw.g[6], w6, o);
        o = f4fma(gw.g[7], w7, o);
        o = f4fma(gw.g[8], w8, o);
        st4s(d, o); d += stride;
        w0=w1; w1=w2; w2=w3; w3=w4; w4=w5; w5=w6; w6=w7; w7=w8;
    }
}

// ---------------- fused pre-kernel: luma + gauss_rho (proven r5-r9) ----------------
__global__ void __launch_bounds__(512) pre_kernel(const float* __restrict__ x,
                                                  float* __restrict__ u0,
                                                  float* __restrict__ rho, GaussW gw) {
    __shared__ __align__(16) float lum[24*76];
    __shared__ __align__(16) float vb[16*72];
    const int tid = threadIdx.x;
    const int X0 = blockIdx.x*64, Y0 = blockIdx.y*16, b = blockIdx.z;
    const float* xb = x + (size_t)b*3*HW;

    if (tid < 24*18) {
        int r = tid/18, qc = tid - r*18;
        int gy = refl(Y0-4+r, H);
        int gc0 = X0-4+4*qc;
        float4 R,G,B;
        if (gc0 >= 0 && gc0+3 <= W-1) {
            const float* px = xb + gy*W + gc0;
            R = ld4s(px); G = ld4s(px+HW); B = ld4s(px+2*HW);
        } else {
            float rr[4], gg[4], bb[4];
#pragma unroll
            for (int j=0;j<4;++j){ int gc = refl(gc0+j, W);
                rr[j]=xb[gy*W+gc]; gg[j]=xb[HW+gy*W+gc]; bb[j]=xb[2*HW+gy*W+gc]; }
            R = make_float4(rr[0],rr[1],rr[2],rr[3]);
            G = make_float4(gg[0],gg[1],gg[2],gg[3]);
            B = make_float4(bb[0],bb[1],bb[2],bb[3]);
        }
        float4 L = make_float4(0.299f*R.x+0.587f*G.x+0.114f*B.x,
                               0.299f*R.y+0.587f*G.y+0.114f*B.y,
                               0.299f*R.z+0.587f*G.z+0.114f*B.z,
                               0.299f*R.w+0.587f*G.w+0.114f*B.w);
        st4s(lum + r*76 + 4*qc, L);
    }
    __syncthreads();
    if (tid < 16*18) {
        int r = tid/18, qc = tid - r*18;
        const float* s = lum + r*76 + 4*qc;
        float4 o = f4mul(gw.g[0], ld4s(s));
#pragma unroll
        for (int t = 1; t < KS; ++t) o = f4fma(gw.g[t], ld4s(s + t*76), o);
        st4s(vb + r*72 + 4*qc, o);
    }
    __syncthreads();
    if (tid < 256) {
        int r = tid>>4, c4 = tid&15;
        const float* s = vb + r*72 + 4*c4;
        float4 q0=ld4s(s), q1=ld4s(s+4), q2=ld4s(s+8);
        float f[12]={q0.x,q0.y,q0.z,q0.w,q1.x,q1.y,q1.z,q1.w,q2.x,q2.y,q2.z,q2.w};
        float o[4];
#pragma unroll
        for (int j=0;j<4;++j) {
            float a = gw.g[0]*f[j];
#pragma unroll
            for (int t=1;t<KS;++t) a = fmaf(gw.g[t], f[j+t], a);
            o[j] = a;
        }
        int gidx = b*HW + (Y0+r)*W + X0 + 4*c4;
        st4s(rho + gidx, make_float4(o[0],o[1],o[2],o[3]));
        st4s(u0 + gidx, ld4s(lum + (r+4)*76 + 4*c4 + 4));
    }
}

// ---------------- fused 2-iteration step, tile 64x32, 1024 threads, 6 phases ----
// r9 structure (the 563us optimum): fine-grained items, predicated-quad phase A,
// ghost-col mirror items folded into V/V2 strided loops. Only change vs r9:
// global loads in H/H2 are issued BEFORE the LDS-dependent accumulation.
// Dynamic LDS (floats), total 24288 (97152 B):
//   p  @0     : 3 x 50x88 (stride 4400)   rows [Y0-9..Y0+41) cols [X0-12..X0+76)
//   v  @13200 : 3 x 42x88 (stride 3696)   rows [Y0-5..Y0+37)
//   u1 @0     : 42x80 (overlays p, dead)  cols [X0-8..X0+72)
//   q  @3360  : 3 x 40x72 (stride 2880)   rows [Y0-4..Y0+36) cols [X0-4..X0+68)
//   w  @13200 : 3 x 32x72 (stride 2304)   rows [Y0..Y0+32)   (overlays v, dead)
#define STEP_LDS_FL 24288
template<bool LAST>
__global__ void __launch_bounds__(1024, 4) step2_kernel(
        const float* __restrict__ uin, float* __restrict__ uout,
        const float* __restrict__ rho,
        const float* __restrict__ dtp, const float* __restrict__ kp,
        GaussW gw)
{
    extern __shared__ __align__(16) float lds[];
    float* p_ = lds;             // 3 x 50x88
    float* v_ = lds + 13200;     // 3 x 42x88
    float* u1 = lds;             // 42x80
    float* q_ = lds + 3360;      // 3 x 40x72
    float* w_ = lds + 13200;     // 3 x 32x72

    const int tid = threadIdx.x;
    const int X0 = blockIdx.x*64, Y0 = blockIdx.y*32, b = blockIdx.z;
    const float* ub = uin + b*HW;
    const float* rb = rho + b*HW;
    const float dt = *dtp;
    const float kk = *kp;
    const float kc = 1.4426950408889634f / (kk*kk);
    const bool eL = (X0 == 0), eR = (X0 == W-64);
    const float4 f4z = make_float4(0.f,0.f,0.f,0.f);

    // ---- Phase A: iter1 Sobel products straight from global u (predicated quads)
    if (tid < 550) {
        int pr = tid / 11, cg = tid - pr*11;
        int c0 = X0 - 12 + 8*cg;
        int p0 = refl(Y0 - 9 + pr, H);
        const float* rc = ub + p0*W;
        const float* rm = rc - W;
        const float* rp = rc + W;
        bool mok = (p0 > 0), pok = (p0 < H-1);
        int cA = c0-4, cB = c0, cC = c0+4, cD = c0+8;
        bool aok = (cA >= 0 && cA <= W-4), bok = (cB >= 0 && cB <= W-4);
        bool cok = (cC >= 0 && cC <= W-4), dok = (cD >= 0 && cD <= W-4);
        float4 Am = (mok&&aok)?ld4s(rm+cA):f4z, Bm = (mok&&bok)?ld4s(rm+cB):f4z;
        float4 Cm = (mok&&cok)?ld4s(rm+cC):f4z, Dm = (mok&&dok)?ld4s(rm+cD):f4z;
        float4 Ac = aok?ld4s(rc+cA):f4z,        Bc = bok?ld4s(rc+cB):f4z;
        float4 Cc = cok?ld4s(rc+cC):f4z,        Dc = dok?ld4s(rc+cD):f4z;
        float4 Ap = (pok&&aok)?ld4s(rp+cA):f4z, Bp = (pok&&bok)?ld4s(rp+cB):f4z;
        float4 Cp = (pok&&cok)?ld4s(rp+cC):f4z, Dp = (pok&&dok)?ld4s(rp+cD):f4z;
        float fm[10]={Am.w,Bm.x,Bm.y,Bm.z,Bm.w,Cm.x,Cm.y,Cm.z,Cm.w,Dm.x};
        float fc[10]={Ac.w,Bc.x,Bc.y,Bc.z,Bc.w,Cc.x,Cc.y,Cc.z,Cc.w,Dc.x};
        float fp[10]={Ap.w,Bp.x,Bp.y,Bp.z,Bp.w,Cp.x,Cp.y,Cp.z,Cp.w,Dp.x};
        float o11[8],o12[8],o22[8];
#pragma unroll
        for (int j=0;j<8;++j) {
            float gx = (fm[j+2]-fm[j]) + 2.f*(fc[j+2]-fc[j]) + (fp[j+2]-fp[j]);
            float gy = (fp[j]-fm[j]) + 2.f*(fp[j+1]-fm[j+1]) + (fp[j+2]-fm[j+2]);
            o11[j]=gx*gx; o12[j]=gx*gy; o22[j]=gy*gy;
        }
        int o = pr*88 + 8*cg;
        st4s(p_+o,        make_float4(o11[0],o11[1],o11[2],o11[3]));
        st4s(p_+o+4,      make_float4(o11[4],o11[5],o11[6],o11[7]));
        st4s(p_+4400+o,   make_float4(o12[0],o12[1],o12[2],o12[3]));
        st4s(p_+4400+o+4, make_float4(o12[4],o12[5],o12[6],o12[7]));
        st4s(p_+8800+o,   make_float4(o22[0],o22[1],o22[2],o22[3]));
        st4s(p_+8800+o+4, make_float4(o22[4],o22[5],o22[6],o22[7]));
    }
    __syncthreads();

    // ---- Phase V: iter1 vertical blur (3-row strips, 924 items) + ghost-col items
    {
        int nTot = 924 + ((eL || eR) ? 1134 : 0);
        for (int i = tid; i < nTot; i += 1024) {
            if (i < 924) {
                int cg = i % 22; int t = i / 22; int strip = t % 14; int pl = t / 14;
                if (eL && cg < 3) continue;      // ghost region, scalar items cover it
                if (eR && cg > 18) continue;
                vblur_strip<3>(p_ + pl*4400, v_ + pl*3696, 4*cg, strip*3, gw, 88);
            } else {
                int g = i - 924;
                int j = 1 + (g % 9); int t = g / 9; int rr = t % 42; int pl = t / 42;
                const float* P = p_ + pl*4400;
                int dst = eL ? (12 - j) : (75 + j);
                int src = eL ? (12 + j) : (75 - j);
                float a = 0.f;
#pragma unroll
                for (int t2 = 0; t2 < KS; ++t2) a = fmaf(gw.g[t2], P[(rr+t2)*88 + src], a);
                (v_ + pl*3696)[rr*88 + dst] = a;
            }
        }
    }
    __syncthreads();

    // ---- Phase H: iter1 horizontal blur + eig + update -> u1 (4px/item, 840 items)
    if (tid < 840) {
        int r = tid/20, qc = tid - r*20;      // r 0..41, qc 0..19
        int uy = Y0-5+r;
        int c0 = X0-8+4*qc;
        // issue global loads FIRST so L2 latency hides under the FMA chain
        bool in0 = (uy>=0 && uy<H) && c0>=0 && c0<=W-4;
        float4 rv0=f4z, uq0=f4z;
        if (in0) { rv0 = ld4s(rb+uy*W+c0); uq0 = ld4s(ub+uy*W+c0); }
        float acc[3][4];
#pragma unroll
        for (int pl=0; pl<3; ++pl) {
            const float* Vp = v_ + pl*3696 + r*88 + 4*qc;
            float4 q0=ld4s(Vp), q1=ld4s(Vp+4), q2=ld4s(Vp+8);
            float f[12]={q0.x,q0.y,q0.z,q0.w,q1.x,q1.y,q1.z,q1.w,q2.x,q2.y,q2.z,q2.w};
#pragma unroll
            for (int j=0;j<4;++j) {
                float s = gw.g[0]*f[j];
#pragma unroll
                for (int t=1;t<KS;++t) s = fmaf(gw.g[t], f[j+t], s);
                acc[pl][j] = s;
            }
        }
        float rva[4]={rv0.x,rv0.y,rv0.z,rv0.w};
        float uqa[4]={uq0.x,uq0.y,uq0.z,uq0.w};
        float res[4];
#pragma unroll
        for (int j=0;j<4;++j)
            res[j] = diffuse(acc[0][j],acc[1][j],acc[2][j],rva[j],uqa[j],dt,kc);
        st4s(u1 + r*80 + 4*qc,
             in0 ? make_float4(res[0],res[1],res[2],res[3]) : f4z);
    }
    __syncthreads();

    // ---- Phase A2: iter2 Sobel products from u1 (4px/item, 720 items)
    if (tid < 720) {
        int pr = tid/18, cg = tid - pr*18;    // pr 0..39, cg 0..17
        int sr = refl(Y0-4+pr, H) - (Y0-5);   // in [1,40]
        const float* rmw = u1 + (sr-1)*80;
        const float* rcw = rmw + 80;
        const float* rpw = rcw + 80;
        float o11[4],o12[4],o22[4];
        bool scalar = (eL && cg==0) || (eR && cg==17);
        if (!scalar) {
            const float* m4 = rmw + 4*cg;
            const float* c4p = rcw + 4*cg;
            const float* p4 = rpw + 4*cg;
            float4 Am=ld4s(m4), Bm=ld4s(m4+4), Cm=ld4s(m4+8);
            float4 Ac=ld4s(c4p), Bc=ld4s(c4p+4), Cc=ld4s(c4p+8);
            float4 Ap=ld4s(p4), Bp=ld4s(p4+4), Cp=ld4s(p4+8);
            float fm[6]={Am.w,Bm.x,Bm.y,Bm.z,Bm.w,Cm.x};
            float fc[6]={Ac.w,Bc.x,Bc.y,Bc.z,Bc.w,Cc.x};
            float fp[6]={Ap.w,Bp.x,Bp.y,Bp.z,Bp.w,Cp.x};
#pragma unroll
            for (int j=0;j<4;++j) {
                float gx = (fm[j+2]-fm[j]) + 2.f*(fc[j+2]-fc[j]) + (fp[j+2]-fp[j]);
                float gy = (fp[j]-fm[j]) + 2.f*(fp[j+1]-fm[j+1]) + (fp[j+2]-fm[j+2]);
                o11[j]=gx*gx; o12[j]=gx*gy; o22[j]=gy*gy;
            }
        } else {
#pragma unroll
            for (int j=0;j<4;++j) {
                int xc = X0 - 4 + 4*cg + j;
                int uc = refl(xc, W) - X0 + 8;    // u1-space col (ghost zeros give pad)
                float gx = (rmw[uc+1]-rmw[uc-1]) + 2.f*(rcw[uc+1]-rcw[uc-1]) + (rpw[uc+1]-rpw[uc-1]);
                float gy = (rpw[uc-1]-rmw[uc-1]) + 2.f*(rpw[uc]-rmw[uc]) + (rpw[uc+1]-rmw[uc+1]);
                o11[j]=gx*gx; o12[j]=gx*gy; o22[j]=gy*gy;
            }
        }
        int o = pr*72 + 4*cg;
        st4s(q_+o,      make_float4(o11[0],o11[1],o11[2],o11[3]));
        st4s(q_+2880+o, make_float4(o12[0],o12[1],o12[2],o12[3]));
        st4s(q_+5760+o, make_float4(o22[0],o22[1],o22[2],o22[3]));
    }
    __syncthreads();

    // ---- Phase V2: iter2 vertical blur (4-row strips, 432 items) + ghost-col items
    {
        int n2 = 432 + ((eL || eR) ? 384 : 0);
        if (tid < n2) {
            if (tid < 432) {
                int cg = tid % 18; int t = tid/18; int strip = t % 8; int pl = t/8;
                bool skip = (eL && cg == 0) || (eR && cg == 17);
                if (!skip)
                    vblur_strip<4>(q_ + pl*2880, w_ + pl*2304, 4*cg, strip*4, gw, 72);
            } else {
                int g = tid - 432;
                int j = 1 + (g & 3); int t = g >> 2; int rr = t % 32; int pl = t / 32;
                const float* Q = q_ + pl*2880;
                int dst = eL ? (4-j) : (67+j);
                int src = eL ? (4+j) : (67-j);
                float a = 0.f;
#pragma unroll
                for (int t2 = 0; t2 < KS; ++t2) a = fmaf(gw.g[t2], Q[(rr+t2)*72 + src], a);
                (w_ + pl*2304)[rr*72 + dst] = a;
            }
        }
    }
    __syncthreads();

    // ---- Phase H2: iter2 horizontal blur + eig + update -> global (512 items)
    if (tid < 512) {
        int r = tid>>4, c4 = tid&15;
        int gidx = (Y0+r)*W + X0 + 4*c4;
        // issue global load FIRST so L2 latency hides under the FMA chain
        float4 rv = ld4s(rb + gidx);
        float4 uq = ld4s(u1 + (r+5)*80 + 4*c4 + 8);
        float acc[3][4];
#pragma unroll
        for (int pl=0; pl<3; ++pl) {
            const float* Vp = w_ + pl*2304 + r*72 + 4*c4;
            float4 q0=ld4s(Vp), q1=ld4s(Vp+4), q2=ld4s(Vp+8);
            float f[12]={q0.x,q0.y,q0.z,q0.w,q1.x,q1.y,q1.z,q1.w,q2.x,q2.y,q2.z,q2.w};
#pragma unroll
            for (int j=0;j<4;++j) {
                float s = gw.g[0]*f[j];
#pragma unroll
                for (int t=1;t<KS;++t) s = fmaf(gw.g[t], f[j+t], s);
                acc[pl][j] = s;
            }
        }
        float rva[4]={rv.x,rv.y,rv.z,rv.w};
        float uqa[4]={uq.x,uq.y,uq.z,uq.w};
        float o[4];
#pragma unroll
        for (int j=0;j<4;++j)
            o[j] = diffuse(acc[0][j],acc[1][j],acc[2][j],rva[j],uqa[j],dt,kc);
        float4 ov = make_float4(o[0],o[1],o[2],o[3]);
        if (LAST) {
            float* ob = uout + (size_t)b*3*HW + gidx;
            st4s(ob, ov); st4s(ob+HW, ov); st4s(ob+2*HW, ov);
        } else {
            st4s(uout + b*HW + gidx, ov);
        }
    }
}

extern "C" void kernel_launch(void* const* d_in, const int* in_sizes, int n_in,
                              void* d_out, int out_size, void* d_ws, size_t ws_size,
                              hipStream_t stream) {
    const float* x   = (const float*)d_in[0];
    const float* dtp = (const float*)d_in[1];
    const float* kp  = (const float*)d_in[2];
    float* out = (float*)d_out;

    float* u_a = (float*)d_ws;
    float* u_b = u_a + BATCH*HW;
    float* rho = u_b + BATCH*HW;

    GaussW gw;
    {
        double s = 0.0, wd[KS];
        for (int i = 0; i < KS; ++i) {
            double xd = (double)i - 4.0;
            wd[i] = exp(-0.5 * (xd/4.0) * (xd/4.0));
            s += wd[i];
        }
        for (int i = 0; i < KS; ++i) gw.g[i] = (float)(wd[i] / s);
    }

    const int dyn_lds = STEP_LDS_FL * 4;   // 97152 B
    (void)hipFuncSetAttribute((const void*)step2_kernel<false>,
                              hipFuncAttributeMaxDynamicSharedMemorySize, dyn_lds);
    (void)hipFuncSetAttribute((const void*)step2_kernel<true>,
                              hipFuncAttributeMaxDynamicSharedMemorySize, dyn_lds);

    dim3 gpre(W/64, H/16, BATCH), bpre(512);
    pre_kernel<<<gpre, bpre, 0, stream>>>(x, u_a, rho, gw);

    dim3 gs(W/64, H/32, BATCH), bs(1024);
    float* cur = u_a;
    float* nxt = u_b;
    for (int it = 0; it < NSTEP-1; ++it) {
        step2_kernel<false><<<gs, bs, dyn_lds, stream>>>(cur, nxt, rho, dtp, kp, gw);
        float* t = cur; cur = nxt; nxt = t;
    }
    step2_kernel<true><<<gs, bs, dyn_lds, stream>>>(cur, out, rho, dtp, kp, gw);
}

// Round 13
// 563.040 us; speedup vs baseline: 1.2170x; 1.0180x over previous
//
#include <hip/hip_runtime.h>
#include <math.h>

#define BATCH 8
#define H 256
#define W 256
#define HW (H*W)
#define KS 9
#define NSTEP 50   // 50 launches x 2 fused iterations = 100

struct GaussW { float g[KS]; };

__device__ __forceinline__ int refl(int i, int n) {
    if (i < 0) i = -i;
    if (i >= n) i = 2*n - 2 - i;
    return i;
}

__device__ __forceinline__ float4 ld4s(const float* p) { return *(const float4*)p; }
__device__ __forceinline__ void st4s(float* p, float4 v) { *(float4*)p = v; }
__device__ __forceinline__ float4 f4mul(float a, float4 x) {
    return make_float4(a*x.x, a*x.y, a*x.z, a*x.w);
}
__device__ __forceinline__ float4 f4fma(float a, float4 x, float4 y) {
    return make_float4(fmaf(a,x.x,y.x), fmaf(a,x.y,y.y), fmaf(a,x.z,y.z), fmaf(a,x.w,y.w));
}

#if defined(__has_builtin)
#  if __has_builtin(__builtin_amdgcn_exp2f)
#    define FEXP2(x) __builtin_amdgcn_exp2f(x)
#  endif
#  if __has_builtin(__builtin_amdgcn_sqrtf)
#    define FSQRT(x) __builtin_amdgcn_sqrtf(x)
#  endif
#endif
#ifndef FEXP2
#  define FEXP2(x) exp2f(x)
#endif
#ifndef FSQRT
#  define FSQRT(x) sqrtf(x)
#endif

// eig + diffusion update. kc = log2(e)/k^2 so exp(-lam^2/k^2) = exp2(-lam^2*kc)
__device__ __forceinline__ float diffuse(float s11, float s12, float s22,
                                         float rv, float u0, float dt, float kc) {
    s11 -= rv; s12 -= rv; s22 -= rv;
    float df = s11 - s22;
    float tm = FSQRT(fmaf(df, df, 4.f*s12*s12));
    float sm = s11 + s22;
    float lam1 = 0.5f*(sm + tm);
    float lam2 = 0.5f*(sm - tm);
    float e1 = FEXP2(-(lam1*lam1)*kc);
    float e2 = FEXP2(-(lam2*lam2)*kc);
    return fmaf(dt, fmaf(e1, lam1, e2*lam2), u0);
}

// register-sliding vertical 9-tap blur strip (b128 LDS in/out)
template<int N>
__device__ __forceinline__ void vblur_strip(const float* __restrict__ P, float* __restrict__ V,
                                            int qoff, int r0, const GaussW gw, int stride) {
    const float* s = P + r0*stride + qoff;
    float4 w0 = ld4s(s); s += stride;
    float4 w1 = ld4s(s); s += stride;
    float4 w2 = ld4s(s); s += stride;
    float4 w3 = ld4s(s); s += stride;
    float4 w4 = ld4s(s); s += stride;
    float4 w5 = ld4s(s); s += stride;
    float4 w6 = ld4s(s); s += stride;
    float4 w7 = ld4s(s); s += stride;
    float* d = V + r0*stride + qoff;
#pragma unroll
    for (int j = 0; j < N; ++j) {
        float4 w8 = ld4s(s); s += stride;
        float4 o = f4mul(gw.g[0], w0);
        o = f4fma(gw.g[1], w1, o);
        o = f4fma(gw.g[2], w2, o);
        o = f4fma(gw.g[3], w3, o);
        o = f4fma(gw.g[4], w4, o);
        o = f4fma(gw.g[5], w5, o);
        o = f4fma(gw.g[6], w6, o);
        o = f4fma(gw.g[7], w7, o);
        o = f4fma(gw.g[8], w8, o);
        st4s(d, o); d += stride;
        w0=w1; w1=w2; w2=w3; w3=w4; w4=w5; w5=w6; w6=w7; w7=w8;
    }
}

// ---------------- fused pre-kernel: luma + gauss_rho (proven r5-r9) ----------------
__global__ void __launch_bounds__(512) pre_kernel(const float* __restrict__ x,
                                                  float* __restrict__ u0,
                                                  float* __restrict__ rho, GaussW gw) {
    __shared__ __align__(16) float lum[24*76];
    __shared__ __align__(16) float vb[16*72];
    const int tid = threadIdx.x;
    const int X0 = blockIdx.x*64, Y0 = blockIdx.y*16, b = blockIdx.z;
    const float* xb = x + (size_t)b*3*HW;

    if (tid < 24*18) {
        int r = tid/18, qc = tid - r*18;
        int gy = refl(Y0-4+r, H);
        int gc0 = X0-4+4*qc;
        float4 R,G,B;
        if (gc0 >= 0 && gc0+3 <= W-1) {
            const float* px = xb + gy*W + gc0;
            R = ld4s(px); G = ld4s(px+HW); B = ld4s(px+2*HW);
        } else {
            float rr[4], gg[4], bb[4];
#pragma unroll
            for (int j=0;j<4;++j){ int gc = refl(gc0+j, W);
                rr[j]=xb[gy*W+gc]; gg[j]=xb[HW+gy*W+gc]; bb[j]=xb[2*HW+gy*W+gc]; }
            R = make_float4(rr[0],rr[1],rr[2],rr[3]);
            G = make_float4(gg[0],gg[1],gg[2],gg[3]);
            B = make_float4(bb[0],bb[1],bb[2],bb[3]);
        }
        float4 L = make_float4(0.299f*R.x+0.587f*G.x+0.114f*B.x,
                               0.299f*R.y+0.587f*G.y+0.114f*B.y,
                               0.299f*R.z+0.587f*G.z+0.114f*B.z,
                               0.299f*R.w+0.587f*G.w+0.114f*B.w);
        st4s(lum + r*76 + 4*qc, L);
    }
    __syncthreads();
    if (tid < 16*18) {
        int r = tid/18, qc = tid - r*18;
        const float* s = lum + r*76 + 4*qc;
        float4 o = f4mul(gw.g[0], ld4s(s));
#pragma unroll
        for (int t = 1; t < KS; ++t) o = f4fma(gw.g[t], ld4s(s + t*76), o);
        st4s(vb + r*72 + 4*qc, o);
    }
    __syncthreads();
    if (tid < 256) {
        int r = tid>>4, c4 = tid&15;
        const float* s = vb + r*72 + 4*c4;
        float4 q0=ld4s(s), q1=ld4s(s+4), q2=ld4s(s+8);
        float f[12]={q0.x,q0.y,q0.z,q0.w,q1.x,q1.y,q1.z,q1.w,q2.x,q2.y,q2.z,q2.w};
        float o[4];
#pragma unroll
        for (int j=0;j<4;++j) {
            float a = gw.g[0]*f[j];
#pragma unroll
            for (int t=1;t<KS;++t) a = fmaf(gw.g[t], f[j+t], a);
            o[j] = a;
        }
        int gidx = b*HW + (Y0+r)*W + X0 + 4*c4;
        st4s(rho + gidx, make_float4(o[0],o[1],o[2],o[3]));
        st4s(u0 + gidx, ld4s(lum + (r+4)*76 + 4*c4 + 4));
    }
}

// ---------------- fused 2-iteration step, tile 64x32, 1024 threads, 6 phases ----
// Measured optimum (563 us, round 9): fine-grained items, predicated-quad phase A,
// ghost-col mirror items folded into V/V2 strided loops, 1 block/CU.
// Dynamic LDS (floats), total 24288 (97152 B):
//   p  @0     : 3 x 50x88 (stride 4400)   rows [Y0-9..Y0+41) cols [X0-12..X0+76)
//   v  @13200 : 3 x 42x88 (stride 3696)   rows [Y0-5..Y0+37)
//   u1 @0     : 42x80 (overlays p, dead)  cols [X0-8..X0+72)
//   q  @3360  : 3 x 40x72 (stride 2880)   rows [Y0-4..Y0+36) cols [X0-4..X0+68)
//   w  @13200 : 3 x 32x72 (stride 2304)   rows [Y0..Y0+32)   (overlays v, dead)
#define STEP_LDS_FL 24288
template<bool LAST>
__global__ void __launch_bounds__(1024, 4) step2_kernel(
        const float* __restrict__ uin, float* __restrict__ uout,
        const float* __restrict__ rho,
        const float* __restrict__ dtp, const float* __restrict__ kp,
        GaussW gw)
{
    extern __shared__ __align__(16) float lds[];
    float* p_ = lds;             // 3 x 50x88
    float* v_ = lds + 13200;     // 3 x 42x88
    float* u1 = lds;             // 42x80
    float* q_ = lds + 3360;      // 3 x 40x72
    float* w_ = lds + 13200;     // 3 x 32x72

    const int tid = threadIdx.x;
    const int X0 = blockIdx.x*64, Y0 = blockIdx.y*32, b = blockIdx.z;
    const float* ub = uin + b*HW;
    const float* rb = rho + b*HW;
    const float dt = *dtp;
    const float kk = *kp;
    const float kc = 1.4426950408889634f / (kk*kk);
    const bool eL = (X0 == 0), eR = (X0 == W-64);
    const float4 f4z = make_float4(0.f,0.f,0.f,0.f);

    // ---- Phase A: iter1 Sobel products straight from global u (predicated quads)
    if (tid < 550) {
        int pr = tid / 11, cg = tid - pr*11;
        int c0 = X0 - 12 + 8*cg;
        int p0 = refl(Y0 - 9 + pr, H);
        const float* rc = ub + p0*W;
        const float* rm = rc - W;
        const float* rp = rc + W;
        bool mok = (p0 > 0), pok = (p0 < H-1);
        int cA = c0-4, cB = c0, cC = c0+4, cD = c0+8;
        bool aok = (cA >= 0 && cA <= W-4), bok = (cB >= 0 && cB <= W-4);
        bool cok = (cC >= 0 && cC <= W-4), dok = (cD >= 0 && cD <= W-4);
        float4 Am = (mok&&aok)?ld4s(rm+cA):f4z, Bm = (mok&&bok)?ld4s(rm+cB):f4z;
        float4 Cm = (mok&&cok)?ld4s(rm+cC):f4z, Dm = (mok&&dok)?ld4s(rm+cD):f4z;
        float4 Ac = aok?ld4s(rc+cA):f4z,        Bc = bok?ld4s(rc+cB):f4z;
        float4 Cc = cok?ld4s(rc+cC):f4z,        Dc = dok?ld4s(rc+cD):f4z;
        float4 Ap = (pok&&aok)?ld4s(rp+cA):f4z, Bp = (pok&&bok)?ld4s(rp+cB):f4z;
        float4 Cp = (pok&&cok)?ld4s(rp+cC):f4z, Dp = (pok&&dok)?ld4s(rp+cD):f4z;
        float fm[10]={Am.w,Bm.x,Bm.y,Bm.z,Bm.w,Cm.x,Cm.y,Cm.z,Cm.w,Dm.x};
        float fc[10]={Ac.w,Bc.x,Bc.y,Bc.z,Bc.w,Cc.x,Cc.y,Cc.z,Cc.w,Dc.x};
        float fp[10]={Ap.w,Bp.x,Bp.y,Bp.z,Bp.w,Cp.x,Cp.y,Cp.z,Cp.w,Dp.x};
        float o11[8],o12[8],o22[8];
#pragma unroll
        for (int j=0;j<8;++j) {
            float gx = (fm[j+2]-fm[j]) + 2.f*(fc[j+2]-fc[j]) + (fp[j+2]-fp[j]);
            float gy = (fp[j]-fm[j]) + 2.f*(fp[j+1]-fm[j+1]) + (fp[j+2]-fm[j+2]);
            o11[j]=gx*gx; o12[j]=gx*gy; o22[j]=gy*gy;
        }
        int o = pr*88 + 8*cg;
        st4s(p_+o,        make_float4(o11[0],o11[1],o11[2],o11[3]));
        st4s(p_+o+4,      make_float4(o11[4],o11[5],o11[6],o11[7]));
        st4s(p_+4400+o,   make_float4(o12[0],o12[1],o12[2],o12[3]));
        st4s(p_+4400+o+4, make_float4(o12[4],o12[5],o12[6],o12[7]));
        st4s(p_+8800+o,   make_float4(o22[0],o22[1],o22[2],o22[3]));
        st4s(p_+8800+o+4, make_float4(o22[4],o22[5],o22[6],o22[7]));
    }
    __syncthreads();

    // ---- Phase V: iter1 vertical blur (3-row strips, 924 items) + ghost-col items
    {
        int nTot = 924 + ((eL || eR) ? 1134 : 0);
        for (int i = tid; i < nTot; i += 1024) {
            if (i < 924) {
                int cg = i % 22; int t = i / 22; int strip = t % 14; int pl = t / 14;
                if (eL && cg < 3) continue;      // ghost region, scalar items cover it
                if (eR && cg > 18) continue;
                vblur_strip<3>(p_ + pl*4400, v_ + pl*3696, 4*cg, strip*3, gw, 88);
            } else {
                int g = i - 924;
                int j = 1 + (g % 9); int t = g / 9; int rr = t % 42; int pl = t / 42;
                const float* P = p_ + pl*4400;
                int dst = eL ? (12 - j) : (75 + j);
                int src = eL ? (12 + j) : (75 - j);
                float a = 0.f;
#pragma unroll
                for (int t2 = 0; t2 < KS; ++t2) a = fmaf(gw.g[t2], P[(rr+t2)*88 + src], a);
                (v_ + pl*3696)[rr*88 + dst] = a;
            }
        }
    }
    __syncthreads();

    // ---- Phase H: iter1 horizontal blur + eig + update -> u1 (4px/item, 840 items)
    if (tid < 840) {
        int r = tid/20, qc = tid - r*20;      // r 0..41, qc 0..19
        int uy = Y0-5+r;
        int c0 = X0-8+4*qc;
        float acc[3][4];
#pragma unroll
        for (int pl=0; pl<3; ++pl) {
            const float* Vp = v_ + pl*3696 + r*88 + 4*qc;
            float4 q0=ld4s(Vp), q1=ld4s(Vp+4), q2=ld4s(Vp+8);
            float f[12]={q0.x,q0.y,q0.z,q0.w,q1.x,q1.y,q1.z,q1.w,q2.x,q2.y,q2.z,q2.w};
#pragma unroll
            for (int j=0;j<4;++j) {
                float s = gw.g[0]*f[j];
#pragma unroll
                for (int t=1;t<KS;++t) s = fmaf(gw.g[t], f[j+t], s);
                acc[pl][j] = s;
            }
        }
        bool in0 = (uy>=0 && uy<H) && c0>=0 && c0<=W-4;
        float4 rv0=f4z, uq0=f4z;
        if (in0) { rv0 = ld4s(rb+uy*W+c0); uq0 = ld4s(ub+uy*W+c0); }
        float rva[4]={rv0.x,rv0.y,rv0.z,rv0.w};
        float uqa[4]={uq0.x,uq0.y,uq0.z,uq0.w};
        float res[4];
#pragma unroll
        for (int j=0;j<4;++j)
            res[j] = diffuse(acc[0][j],acc[1][j],acc[2][j],rva[j],uqa[j],dt,kc);
        st4s(u1 + r*80 + 4*qc,
             in0 ? make_float4(res[0],res[1],res[2],res[3]) : f4z);
    }
    __syncthreads();

    // ---- Phase A2: iter2 Sobel products from u1 (4px/item, 720 items)
    if (tid < 720) {
        int pr = tid/18, cg = tid - pr*18;    // pr 0..39, cg 0..17
        int sr = refl(Y0-4+pr, H) - (Y0-5);   // in [1,40]
        const float* rmw = u1 + (sr-1)*80;
        const float* rcw = rmw + 80;
        const float* rpw = rcw + 80;
        float o11[4],o12[4],o22[4];
        bool scalar = (eL && cg==0) || (eR && cg==17);
        if (!scalar) {
            const float* m4 = rmw + 4*cg;
            const float* c4p = rcw + 4*cg;
            const float* p4 = rpw + 4*cg;
            float4 Am=ld4s(m4), Bm=ld4s(m4+4), Cm=ld4s(m4+8);
            float4 Ac=ld4s(c4p), Bc=ld4s(c4p+4), Cc=ld4s(c4p+8);
            float4 Ap=ld4s(p4), Bp=ld4s(p4+4), Cp=ld4s(p4+8);
            float fm[6]={Am.w,Bm.x,Bm.y,Bm.z,Bm.w,Cm.x};
            float fc[6]={Ac.w,Bc.x,Bc.y,Bc.z,Bc.w,Cc.x};
            float fp[6]={Ap.w,Bp.x,Bp.y,Bp.z,Bp.w,Cp.x};
#pragma unroll
            for (int j=0;j<4;++j) {
                float gx = (fm[j+2]-fm[j]) + 2.f*(fc[j+2]-fc[j]) + (fp[j+2]-fp[j]);
                float gy = (fp[j]-fm[j]) + 2.f*(fp[j+1]-fm[j+1]) + (fp[j+2]-fm[j+2]);
                o11[j]=gx*gx; o12[j]=gx*gy; o22[j]=gy*gy;
            }
        } else {
#pragma unroll
            for (int j=0;j<4;++j) {
                int xc = X0 - 4 + 4*cg + j;
                int uc = refl(xc, W) - X0 + 8;    // u1-space col (ghost zeros give pad)
                float gx = (rmw[uc+1]-rmw[uc-1]) + 2.f*(rcw[uc+1]-rcw[uc-1]) + (rpw[uc+1]-rpw[uc-1]);
                float gy = (rpw[uc-1]-rmw[uc-1]) + 2.f*(rpw[uc]-rmw[uc]) + (rpw[uc+1]-rmw[uc+1]);
                o11[j]=gx*gx; o12[j]=gx*gy; o22[j]=gy*gy;
            }
        }
        int o = pr*72 + 4*cg;
        st4s(q_+o,      make_float4(o11[0],o11[1],o11[2],o11[3]));
        st4s(q_+2880+o, make_float4(o12[0],o12[1],o12[2],o12[3]));
        st4s(q_+5760+o, make_float4(o22[0],o22[1],o22[2],o22[3]));
    }
    __syncthreads();

    // ---- Phase V2: iter2 vertical blur (4-row strips, 432 items) + ghost-col items
    {
        int n2 = 432 + ((eL || eR) ? 384 : 0);
        if (tid < n2) {
            if (tid < 432) {
                int cg = tid % 18; int t = tid/18; int strip = t % 8; int pl = t/8;
                bool skip = (eL && cg == 0) || (eR && cg == 17);
                if (!skip)
                    vblur_strip<4>(q_ + pl*2880, w_ + pl*2304, 4*cg, strip*4, gw, 72);
            } else {
                int g = tid - 432;
                int j = 1 + (g & 3); int t = g >> 2; int rr = t % 32; int pl = t / 32;
                const float* Q = q_ + pl*2880;
                int dst = eL ? (4-j) : (67+j);
                int src = eL ? (4+j) : (67-j);
                float a = 0.f;
#pragma unroll
                for (int t2 = 0; t2 < KS; ++t2) a = fmaf(gw.g[t2], Q[(rr+t2)*72 + src], a);
                (w_ + pl*2304)[rr*72 + dst] = a;
            }
        }
    }
    __syncthreads();

    // ---- Phase H2: iter2 horizontal blur + eig + update -> global (512 items)
    if (tid < 512) {
        int r = tid>>4, c4 = tid&15;
        float acc[3][4];
#pragma unroll
        for (int pl=0; pl<3; ++pl) {
            const float* Vp = w_ + pl*2304 + r*72 + 4*c4;
            float4 q0=ld4s(Vp), q1=ld4s(Vp+4), q2=ld4s(Vp+8);
            float f[12]={q0.x,q0.y,q0.z,q0.w,q1.x,q1.y,q1.z,q1.w,q2.x,q2.y,q2.z,q2.w};
#pragma unroll
            for (int j=0;j<4;++j) {
                float s = gw.g[0]*f[j];
#pragma unroll
                for (int t=1;t<KS;++t) s = fmaf(gw.g[t], f[j+t], s);
                acc[pl][j] = s;
            }
        }
        int gidx = (Y0+r)*W + X0 + 4*c4;
        float4 rv = ld4s(rb + gidx);
        float4 uq = ld4s(u1 + (r+5)*80 + 4*c4 + 8);
        float rva[4]={rv.x,rv.y,rv.z,rv.w};
        float uqa[4]={uq.x,uq.y,uq.z,uq.w};
        float o[4];
#pragma unroll
        for (int j=0;j<4;++j)
            o[j] = diffuse(acc[0][j],acc[1][j],acc[2][j],rva[j],uqa[j],dt,kc);
        float4 ov = make_float4(o[0],o[1],o[2],o[3]);
        if (LAST) {
            float* ob = uout + (size_t)b*3*HW + gidx;
            st4s(ob, ov); st4s(ob+HW, ov); st4s(ob+2*HW, ov);
        } else {
            st4s(uout + b*HW + gidx, ov);
        }
    }
}

extern "C" void kernel_launch(void* const* d_in, const int* in_sizes, int n_in,
                              void* d_out, int out_size, void* d_ws, size_t ws_size,
                              hipStream_t stream) {
    const float* x   = (const float*)d_in[0];
    const float* dtp = (const float*)d_in[1];
    const float* kp  = (const float*)d_in[2];
    float* out = (float*)d_out;

    float* u_a = (float*)d_ws;
    float* u_b = u_a + BATCH*HW;
    float* rho = u_b + BATCH*HW;

    GaussW gw;
    {
        double s = 0.0, wd[KS];
        for (int i = 0; i < KS; ++i) {
            double xd = (double)i - 4.0;
            wd[i] = exp(-0.5 * (xd/4.0) * (xd/4.0));
            s += wd[i];
        }
        for (int i = 0; i < KS; ++i) gw.g[i] = (float)(wd[i] / s);
    }

    const int dyn_lds = STEP_LDS_FL * 4;   // 97152 B
    (void)hipFuncSetAttribute((const void*)step2_kernel<false>,
                              hipFuncAttributeMaxDynamicSharedMemorySize, dyn_lds);
    (void)hipFuncSetAttribute((const void*)step2_kernel<true>,
                              hipFuncAttributeMaxDynamicSharedMemorySize, dyn_lds);

    dim3 gpre(W/64, H/16, BATCH), bpre(512);
    pre_kernel<<<gpre, bpre, 0, stream>>>(x, u_a, rho, gw);

    dim3 gs(W/64, H/32, BATCH), bs(1024);
    float* cur = u_a;
    float* nxt = u_b;
    for (int it = 0; it < NSTEP-1; ++it) {
        step2_kernel<false><<<gs, bs, dyn_lds, stream>>>(cur, nxt, rho, dtp, kp, gw);
        float* t = cur; cur = nxt; nxt = t;
    }
    step2_kernel<true><<<gs, bs, dyn_lds, stream>>>(cur, out, rho, dtp, kp, gw);
}